// Round 3
// baseline (202.740 us; speedup 1.0000x reference)
//
#include <hip/hip_runtime.h>
#include <math.h>

#define BB 8
#define NN 2000
#define CC 81
#define NPAD 2048
#define MAXI 100
#define HH 512
#define WW 512

// ---------------------------------------------------------------------------
// Kernel A: per-proposal class argmax, delta refine, validity, sort key.
// One wave (64 lanes) per proposal slot (padded to NPAD per batch so the
// rank kernel sees a full 2048-key array). Coalesced prob reads, shuffle
// argmax. key = sortable(score if valid else -inf)<<32 | (0xFFFFFFFF - n):
// descending u64 order == stable argsort(score desc, idx asc).
// ---------------------------------------------------------------------------
__global__ void k_refine(const float* __restrict__ rois,
                         const float* __restrict__ probs,
                         const float* __restrict__ deltas,
                         const float* __restrict__ stdv,
                         float* __restrict__ score, int* __restrict__ cls,
                         int* __restrict__ valid, float* __restrict__ box,
                         unsigned long long* __restrict__ gkeys) {
#pragma clang fp contract(off)
  int g = blockIdx.x * 4 + (threadIdx.x >> 6);
  if (g >= BB * NPAD) return;
  int lane = threadIdx.x & 63;
  int b = g >> 11, n = g & (NPAD - 1);
  if (n >= NN) {                      // pad slot: key only
    if (lane == 0) {
      unsigned u = __float_as_uint(-INFINITY);
      u = ~u;                         // sign set -> ~u
      gkeys[b * NPAD + n] =
          ((unsigned long long)u << 32) | (0xFFFFFFFFu - (unsigned)n);
    }
    return;
  }
  const float* pp = probs + ((size_t)b * NN + n) * CC;
  float best = -INFINITY;
  int bc = CC;
  for (int c = lane; c < CC; c += 64) {
    float p = pp[c];
    if (p > best) { best = p; bc = c; }   // per-lane stride keeps first max
  }
  // cross-lane argmax, first-occurrence tie-break (smaller class wins)
  for (int off = 32; off; off >>= 1) {
    float ob = __shfl_xor(best, off, 64);
    int oc = __shfl_xor(bc, off, 64);
    if (ob > best || (ob == best && oc < bc)) { best = ob; bc = oc; }
  }
  if (lane == 0) {
    int idx = b * NPAD + n;
    const float* r = rois + ((size_t)b * NN + n) * 4;
    const float* dd = deltas + (((size_t)b * NN + n) * CC + bc) * 4;
    float d0 = dd[0] * stdv[0], d1 = dd[1] * stdv[1];
    float d2 = dd[2] * stdv[2], d3 = dd[3] * stdv[3];
    float y1 = r[0], x1 = r[1], y2 = r[2], x2 = r[3];
    float h = y2 - y1, w = x2 - x1;
    float cy = y1 + 0.5f * h + d0 * h;
    float cx = x1 + 0.5f * w + d1 * w;
    h = h * (float)exp((double)d2);   // double path ~= correctly-rounded f32 exp
    w = w * (float)exp((double)d3);
    float ny1 = cy - 0.5f * h, nx1 = cx - 0.5f * w;
    float ny2 = cy + 0.5f * h, nx2 = cx + 0.5f * w;
    ny1 = fminf(fmaxf(ny1, 0.f), 1.f);
    nx1 = fminf(fmaxf(nx1, 0.f), 1.f);
    ny2 = fminf(fmaxf(ny2, 0.f), 1.f);
    nx2 = fminf(fmaxf(nx2, 0.f), 1.f);
    box[idx * 4 + 0] = ny1;
    box[idx * 4 + 1] = nx1;
    box[idx * 4 + 2] = ny2;
    box[idx * 4 + 3] = nx2;
    score[idx] = best;
    cls[idx] = bc;
    int v = (bc > 0 && best >= 0.05f) ? 1 : 0;
    valid[idx] = v;
    float ks = v ? best : -INFINITY;
    unsigned u = __float_as_uint(ks);
    u = (u & 0x80000000u) ? ~u : (u | 0x80000000u);
    gkeys[idx] = ((unsigned long long)u << 32) | (0xFFFFFFFFu - (unsigned)n);
  }
}

// ---------------------------------------------------------------------------
// Kernel B (v3): rank sort via SCALAR loads. Keys are unique, so
// rank[i] = #{j : key[j] > key[i]} is a perfect permutation. The scan
// address gk[j] is wave-uniform -> compiler emits s_load through the
// constant cache (16 KB key stream, K$-resident); the loop is pure VALU
// (v_cmp_gt_u64 + add), no LDS, no barriers.
// ---------------------------------------------------------------------------
__global__ void k_rank(const unsigned long long* __restrict__ gkeys,
                       const float* __restrict__ score, const int* __restrict__ cls,
                       const int* __restrict__ valid, const float* __restrict__ box,
                       float* __restrict__ sscore, int* __restrict__ scls,
                       int* __restrict__ svalid, float* __restrict__ sbox) {
  int b = blockIdx.x >> 3, part = blockIdx.x & 7, tid = threadIdx.x;
  int me = part * 256 + tid;
  const unsigned long long* gk = gkeys + b * NPAD;
  unsigned long long myk = gk[me];
  int rank = 0;
#pragma unroll 8
  for (int j = 0; j < NPAD; j++) rank += (gk[j] > myk) ? 1 : 0;
  int o = b * NPAD + rank;
  if (me < NN) {
    int ii = b * NPAD + me;
    sscore[o] = score[ii];
    scls[o] = cls[ii];
    svalid[o] = valid[ii];
    ((float4*)sbox)[o] = ((const float4*)box)[ii];
  } else {
    sscore[o] = 0.f; scls[o] = 0; svalid[o] = 0;
    ((float4*)sbox)[o] = make_float4(0.f, 0.f, 0.f, 0.f);
  }
}

// ---------------------------------------------------------------------------
// Kernel C: greedy sequential NMS, one wave per batch.
// Candidates prefetched 64 at a time (coalesced float4/lane), broadcast via
// shuffles. Kept set lives in REGISTERS: kept index t==lane in slot0,
// t==64+lane in slot1; the owner lane captures the already-broadcast values,
// so no LDS and no barriers at all. Early-exit at kept==100 (== top_k of kept
// since the list is score-sorted). Per-class count<100 is vacuous before
// total kept reaches 100; cross-class IoU is 0 by the class-offset trick.
// ---------------------------------------------------------------------------
__global__ void k_nms(const float* __restrict__ sscore, const int* __restrict__ scls,
                      const int* __restrict__ svalid, const float* __restrict__ sbox,
                      float* __restrict__ det) {
#pragma clang fp contract(off)
  int b = blockIdx.x, lane = threadIdx.x;
  int kept = 0;
  bool done = false;
  // register-resident kept boxes (offset coords) + area
  float k0y1 = 0.f, k0x1 = 0.f, k0y2 = 0.f, k0x2 = 0.f, k0a = 0.f;
  float k1y1 = 0.f, k1x1 = 0.f, k1y2 = 0.f, k1x2 = 0.f, k1a = 0.f;
  for (int base = 0; base < NN && !done; base += 64) {
    int o = b * NPAD + base + lane;
    float4 bx = ((const float4*)sbox)[o];
    int lv = svalid[o];
    int lc = scls[o];
    float lsc = sscore[o];
    int lim = (NN - base < 64) ? (NN - base) : 64;
    for (int j = 0; j < lim; j++) {
      int v = __shfl(lv, j, 64);
      if (!v) { done = true; break; }   // sorted: all invalid at the end
      float y1 = __shfl(bx.x, j, 64);
      float x1 = __shfl(bx.y, j, 64);
      float y2 = __shfl(bx.z, j, 64);
      float x2 = __shfl(bx.w, j, 64);
      int c = __shfl(lc, j, 64);
      float off = 2.0f * (float)c;
      float oy1 = y1 + off, ox1 = x1 + off, oy2 = y2 + off, ox2 = x2 + off;
      float area_i = (oy2 - oy1) * (ox2 - ox1);
      bool pred = false;
      if (lane < kept) {
        float yy1 = fmaxf(oy1, k0y1), xx1 = fmaxf(ox1, k0x1);
        float yy2 = fminf(oy2, k0y2), xx2 = fminf(ox2, k0x2);
        float inter = fmaxf(yy2 - yy1, 0.f) * fmaxf(xx2 - xx1, 0.f);
        float uni = (area_i + k0a) - inter;
        pred = (inter / fmaxf(uni, 1e-12f)) > 0.3f;
      }
      if (64 + lane < kept) {
        float yy1 = fmaxf(oy1, k1y1), xx1 = fmaxf(ox1, k1x1);
        float yy2 = fminf(oy2, k1y2), xx2 = fminf(ox2, k1x2);
        float inter = fmaxf(yy2 - yy1, 0.f) * fmaxf(xx2 - xx1, 0.f);
        float uni = (area_i + k1a) - inter;
        pred = pred || ((inter / fmaxf(uni, 1e-12f)) > 0.3f);
      }
      if (__ballot(pred) == 0ULL) {            // wave-uniform accept
        if (kept < 64) {
          if (lane == kept) { k0y1 = oy1; k0x1 = ox1; k0y2 = oy2; k0x2 = ox2; k0a = area_i; }
        } else {
          if (lane == kept - 64) { k1y1 = oy1; k1x1 = ox1; k1y2 = oy2; k1x2 = ox2; k1a = area_i; }
        }
        float sc = __shfl(lsc, j, 64);
        if (lane == 0) {
          float* dr = det + ((size_t)b * MAXI + kept) * 6;
          dr[0] = y1; dr[1] = x1; dr[2] = y2; dr[3] = x2;
          dr[4] = (float)c; dr[5] = sc;
        }
        kept++;
        if (kept == MAXI) { done = true; break; }
      }
    }
  }
  // zero-fill remaining det rows (d_out is poisoned 0xAA)
  int rem = (MAXI - kept) * 6;
  float* dr0 = det + ((size_t)b * MAXI + kept) * 6;
  for (int t = lane; t < rem; t += 64) dr0[t] = 0.f;
}

// ---------------------------------------------------------------------------
// Kernel D (v2): attention mask. One block per (batch, row); 256 threads,
// 2 pixels per thread. Compact boxes covering this row's y into LDS once,
// then per-pixel x-interval tests (broadcast LDS reads, conflict-free).
// ---------------------------------------------------------------------------
__global__ void k_mask(const float* __restrict__ det, float* __restrict__ mask) {
  __shared__ float lx1[MAXI], lx2[MAXI];
  __shared__ int cnt;
  int x = blockIdx.x;
  int h = x & (HH - 1);
  int b = x >> 9;
  int tid = threadIdx.x;
  if (tid == 0) cnt = 0;
  __syncthreads();
  float ys = ((float)h + 0.5f) * (1.0f / 512.0f);
  if (tid < MAXI) {
    const float* dr = det + ((size_t)b * MAXI + tid) * 6;
    float y1 = dr[0], bx1 = dr[1], y2 = dr[2], bx2 = dr[3];
    if (ys >= y1 && ys < y2) {  // zero (padded) boxes cover nothing
      int p = atomicAdd(&cnt, 1);
      lx1[p] = bx1; lx2[p] = bx2;
    }
  }
  __syncthreads();
  float xs0 = ((float)tid + 0.5f) * (1.0f / 512.0f);
  float xs1 = ((float)(tid + 256) + 0.5f) * (1.0f / 512.0f);
  bool c0 = false, c1 = false;
  int n = cnt;
  for (int t = 0; t < n; t++) {
    float a = lx1[t], bq = lx2[t];
    c0 = c0 || (xs0 >= a && xs0 < bq);
    c1 = c1 || (xs1 >= a && xs1 < bq);
  }
  float* row = mask + ((size_t)b * HH + h) * WW;
  row[tid] = c0 ? 1.0f : 0.0f;
  row[tid + 256] = c1 ? 1.0f : 0.0f;
}

// ---------------------------------------------------------------------------
extern "C" void kernel_launch(void* const* d_in, const int* in_sizes, int n_in,
                              void* d_out, int out_size, void* d_ws, size_t ws_size,
                              hipStream_t stream) {
  const float* rois = (const float*)d_in[0];
  const float* probs = (const float*)d_in[1];
  const float* deltas = (const float*)d_in[2];
  const float* stdv = (const float*)d_in[3];
  float* out = (float*)d_out;
  float* det = out;                  // [8,100,6] = 4800 floats
  float* mask = out + BB * MAXI * 6; // [8,512,512]

  char* p = (char*)d_ws;
  unsigned long long* gkeys = (unsigned long long*)p; p += (size_t)BB * NPAD * 8;
  float* box    = (float*)p; p += (size_t)BB * NPAD * 16;
  float* sbox   = (float*)p; p += (size_t)BB * NPAD * 16;
  float* score  = (float*)p; p += (size_t)BB * NPAD * 4;
  float* sscore = (float*)p; p += (size_t)BB * NPAD * 4;
  int*   cls    = (int*)p;   p += (size_t)BB * NPAD * 4;
  int*   scls   = (int*)p;   p += (size_t)BB * NPAD * 4;
  int*   valid  = (int*)p;   p += (size_t)BB * NPAD * 4;
  int*   svalid = (int*)p;   p += (size_t)BB * NPAD * 4;

  k_refine<<<(BB * NPAD) / 4, 256, 0, stream>>>(rois, probs, deltas, stdv,
                                                score, cls, valid, box, gkeys);
  k_rank<<<BB * 8, 256, 0, stream>>>(gkeys, score, cls, valid, box,
                                     sscore, scls, svalid, sbox);
  k_nms<<<BB, 64, 0, stream>>>(sscore, scls, svalid, sbox, det);
  k_mask<<<BB * HH, 256, 0, stream>>>(det, mask);
}

// Round 4
// 136.789 us; speedup vs baseline: 1.4821x; 1.4821x over previous
//
#include <hip/hip_runtime.h>
#include <math.h>

#define BB 8
#define NN 2000
#define CC 81
#define NPAD 2048
#define MAXI 100
#define HH 512
#define WW 512

// ---------------------------------------------------------------------------
// Kernel A: per-proposal class argmax, delta refine, validity, sort key.
// One wave (64 lanes) per proposal slot (padded to NPAD per batch so the
// rank kernels see a full 2048-key array). Coalesced prob reads, shuffle
// argmax. key = sortable(score if valid else -inf)<<32 | (0xFFFFFFFF - n):
// descending u64 order == stable argsort(score desc, idx asc).
// ---------------------------------------------------------------------------
__global__ void k_refine(const float* __restrict__ rois,
                         const float* __restrict__ probs,
                         const float* __restrict__ deltas,
                         const float* __restrict__ stdv,
                         float* __restrict__ score, int* __restrict__ cls,
                         int* __restrict__ valid, float* __restrict__ box,
                         unsigned long long* __restrict__ gkeys) {
#pragma clang fp contract(off)
  int g = blockIdx.x * 4 + (threadIdx.x >> 6);
  if (g >= BB * NPAD) return;
  int lane = threadIdx.x & 63;
  int b = g >> 11, n = g & (NPAD - 1);
  if (n >= NN) {                      // pad slot: sentinel key + invalid
    if (lane == 0) {
      unsigned u = __float_as_uint(-INFINITY);
      u = ~u;                         // sign set -> ~u
      gkeys[b * NPAD + n] =
          ((unsigned long long)u << 32) | (0xFFFFFFFFu - (unsigned)n);
      valid[b * NPAD + n] = 0;        // NMS may gather this slot; ws is poisoned
    }
    return;
  }
  const float* pp = probs + ((size_t)b * NN + n) * CC;
  float best = -INFINITY;
  int bc = CC;
  for (int c = lane; c < CC; c += 64) {
    float p = pp[c];
    if (p > best) { best = p; bc = c; }   // per-lane stride keeps first max
  }
  // cross-lane argmax, first-occurrence tie-break (smaller class wins)
  for (int off = 32; off; off >>= 1) {
    float ob = __shfl_xor(best, off, 64);
    int oc = __shfl_xor(bc, off, 64);
    if (ob > best || (ob == best && oc < bc)) { best = ob; bc = oc; }
  }
  if (lane == 0) {
    int idx = b * NPAD + n;
    const float* r = rois + ((size_t)b * NN + n) * 4;
    const float* dd = deltas + (((size_t)b * NN + n) * CC + bc) * 4;
    float d0 = dd[0] * stdv[0], d1 = dd[1] * stdv[1];
    float d2 = dd[2] * stdv[2], d3 = dd[3] * stdv[3];
    float y1 = r[0], x1 = r[1], y2 = r[2], x2 = r[3];
    float h = y2 - y1, w = x2 - x1;
    float cy = y1 + 0.5f * h + d0 * h;
    float cx = x1 + 0.5f * w + d1 * w;
    h = h * (float)exp((double)d2);   // double path ~= correctly-rounded f32 exp
    w = w * (float)exp((double)d3);
    float ny1 = cy - 0.5f * h, nx1 = cx - 0.5f * w;
    float ny2 = cy + 0.5f * h, nx2 = cx + 0.5f * w;
    ny1 = fminf(fmaxf(ny1, 0.f), 1.f);
    nx1 = fminf(fmaxf(nx1, 0.f), 1.f);
    ny2 = fminf(fmaxf(ny2, 0.f), 1.f);
    nx2 = fminf(fmaxf(nx2, 0.f), 1.f);
    box[idx * 4 + 0] = ny1;
    box[idx * 4 + 1] = nx1;
    box[idx * 4 + 2] = ny2;
    box[idx * 4 + 3] = nx2;
    score[idx] = best;
    cls[idx] = bc;
    int v = (bc > 0 && best >= 0.05f) ? 1 : 0;
    valid[idx] = v;
    float ks = v ? best : -INFINITY;
    unsigned u = __float_as_uint(ks);
    u = (u & 0x80000000u) ? ~u : (u | 0x80000000u);
    gkeys[idx] = ((unsigned long long)u << 32) | (0xFFFFFFFFu - (unsigned)n);
  }
}

// ---------------------------------------------------------------------------
// Kernel B1 (v4): partial rank counts. Keys unique -> rank is a perfect
// permutation. Grid = (batch, i-part, j-part) = 512 blocks: 8x more
// parallelism than one-block-per-batch. Each thread owns key i (register)
// and scans a 256-key j-chunk staged in LDS (wave-uniform address ->
// broadcast, conflict-free). 256 compares/thread, no atomics.
// ---------------------------------------------------------------------------
__global__ void k_rankp(const unsigned long long* __restrict__ gkeys,
                        int* __restrict__ partial) {
  __shared__ unsigned long long sk[256];
  int blk = blockIdx.x;                 // b*64 + ip*8 + jp
  int jp = blk & 7, ip = (blk >> 3) & 7, b = blk >> 6;
  int tid = threadIdx.x;
  sk[tid] = gkeys[b * NPAD + jp * 256 + tid];
  unsigned long long myk = gkeys[b * NPAD + ip * 256 + tid];
  __syncthreads();
  int cnt = 0;
#pragma unroll 8
  for (int j = 0; j < 256; j++) cnt += (sk[j] > myk) ? 1 : 0;
  partial[(b * 8 + jp) * NPAD + ip * 256 + tid] = cnt;
}

// ---------------------------------------------------------------------------
// Kernel B2 (v4): sum the 8 partials per element -> rank, scatter the
// inverse permutation: perm[rank] = original index. 16384 threads total.
// ---------------------------------------------------------------------------
__global__ void k_perm(const int* __restrict__ partial, int* __restrict__ perm) {
  int t = blockIdx.x * 256 + threadIdx.x;   // 0..16383
  int b = t >> 11, i = t & (NPAD - 1);
  int rank = 0;
#pragma unroll
  for (int jp = 0; jp < 8; jp++) rank += partial[(b * 8 + jp) * NPAD + i];
  perm[b * NPAD + rank] = i;
}

// ---------------------------------------------------------------------------
// Kernel C (v3): greedy sequential NMS, one wave per batch. Candidates
// gathered 64 at a time through perm (only ~2-3 chunks needed before
// kept==100), broadcast via shuffles. Kept set lives in REGISTERS (slot0:
// kept idx==lane, slot1: kept idx==64+lane); no LDS, no barriers.
// Early-exit at kept==100 (== top_k of kept since list is score-sorted).
// Per-class count<100 is vacuous before total kept reaches 100; cross-class
// IoU is 0 by the class-offset trick.
// ---------------------------------------------------------------------------
__global__ void k_nms(const float* __restrict__ score, const int* __restrict__ cls,
                      const int* __restrict__ valid, const float* __restrict__ box,
                      const int* __restrict__ perm, float* __restrict__ det) {
#pragma clang fp contract(off)
  int b = blockIdx.x, lane = threadIdx.x;
  int kept = 0;
  bool done = false;
  // register-resident kept boxes (offset coords) + area
  float k0y1 = 0.f, k0x1 = 0.f, k0y2 = 0.f, k0x2 = 0.f, k0a = 0.f;
  float k1y1 = 0.f, k1x1 = 0.f, k1y2 = 0.f, k1x2 = 0.f, k1a = 0.f;
  for (int base = 0; base < NN && !done; base += 64) {
    int pi = perm[b * NPAD + base + lane];
    int o = b * NPAD + pi;
    float4 bx = ((const float4*)box)[o];
    int lv = valid[o];
    int lc = cls[o];
    float lsc = score[o];
    int lim = (NN - base < 64) ? (NN - base) : 64;
    for (int j = 0; j < lim; j++) {
      int v = __shfl(lv, j, 64);
      if (!v) { done = true; break; }   // sorted: all invalid at the end
      float y1 = __shfl(bx.x, j, 64);
      float x1 = __shfl(bx.y, j, 64);
      float y2 = __shfl(bx.z, j, 64);
      float x2 = __shfl(bx.w, j, 64);
      int c = __shfl(lc, j, 64);
      float off = 2.0f * (float)c;
      float oy1 = y1 + off, ox1 = x1 + off, oy2 = y2 + off, ox2 = x2 + off;
      float area_i = (oy2 - oy1) * (ox2 - ox1);
      bool pred = false;
      if (lane < kept) {
        float yy1 = fmaxf(oy1, k0y1), xx1 = fmaxf(ox1, k0x1);
        float yy2 = fminf(oy2, k0y2), xx2 = fminf(ox2, k0x2);
        float inter = fmaxf(yy2 - yy1, 0.f) * fmaxf(xx2 - xx1, 0.f);
        float uni = (area_i + k0a) - inter;
        pred = (inter / fmaxf(uni, 1e-12f)) > 0.3f;
      }
      if (64 + lane < kept) {
        float yy1 = fmaxf(oy1, k1y1), xx1 = fmaxf(ox1, k1x1);
        float yy2 = fminf(oy2, k1y2), xx2 = fminf(ox2, k1x2);
        float inter = fmaxf(yy2 - yy1, 0.f) * fmaxf(xx2 - xx1, 0.f);
        float uni = (area_i + k1a) - inter;
        pred = pred || ((inter / fmaxf(uni, 1e-12f)) > 0.3f);
      }
      if (__ballot(pred) == 0ULL) {            // wave-uniform accept
        if (kept < 64) {
          if (lane == kept) { k0y1 = oy1; k0x1 = ox1; k0y2 = oy2; k0x2 = ox2; k0a = area_i; }
        } else {
          if (lane == kept - 64) { k1y1 = oy1; k1x1 = ox1; k1y2 = oy2; k1x2 = ox2; k1a = area_i; }
        }
        float sc = __shfl(lsc, j, 64);
        if (lane == 0) {
          float* dr = det + ((size_t)b * MAXI + kept) * 6;
          dr[0] = y1; dr[1] = x1; dr[2] = y2; dr[3] = x2;
          dr[4] = (float)c; dr[5] = sc;
        }
        kept++;
        if (kept == MAXI) { done = true; break; }
      }
    }
  }
  // zero-fill remaining det rows (d_out is poisoned 0xAA)
  int rem = (MAXI - kept) * 6;
  float* dr0 = det + ((size_t)b * MAXI + kept) * 6;
  for (int t = lane; t < rem; t += 64) dr0[t] = 0.f;
}

// ---------------------------------------------------------------------------
// Kernel D (v3): attention mask. One block per (batch, row); 256 threads,
// 2 pixels per thread. Boxes covering this row's y compacted into LDS via
// ballot+popcount prefix (no serialized atomics), then per-pixel x tests
// (broadcast LDS reads, conflict-free).
// ---------------------------------------------------------------------------
__global__ void k_mask(const float* __restrict__ det, float* __restrict__ mask) {
  __shared__ float lx1[MAXI], lx2[MAXI];
  __shared__ unsigned long long wmask[4];
  int x = blockIdx.x;
  int h = x & (HH - 1);
  int b = x >> 9;
  int tid = threadIdx.x;
  int wv = tid >> 6, ln = tid & 63;
  float ys = ((float)h + 0.5f) * (1.0f / 512.0f);
  bool inb = false;
  float bx1 = 0.f, bx2 = 0.f;
  if (tid < MAXI) {
    const float* dr = det + ((size_t)b * MAXI + tid) * 6;
    float y1 = dr[0], y2 = dr[2];
    bx1 = dr[1]; bx2 = dr[3];
    inb = (ys >= y1 && ys < y2);   // zero (padded) boxes cover nothing
  }
  unsigned long long bm = __ballot(inb);
  if (ln == 0) wmask[wv] = bm;
  __syncthreads();
  int n = __popcll(wmask[0]) + __popcll(wmask[1]);  // tid<100 only in waves 0,1
  if (inb) {
    int pos = (wv ? __popcll(wmask[0]) : 0) +
              __popcll(bm & ((1ULL << ln) - 1ULL));
    lx1[pos] = bx1; lx2[pos] = bx2;
  }
  __syncthreads();
  float xs0 = ((float)tid + 0.5f) * (1.0f / 512.0f);
  float xs1 = ((float)(tid + 256) + 0.5f) * (1.0f / 512.0f);
  bool c0 = false, c1 = false;
  for (int t = 0; t < n; t++) {
    float a = lx1[t], bq = lx2[t];
    c0 = c0 || (xs0 >= a && xs0 < bq);
    c1 = c1 || (xs1 >= a && xs1 < bq);
  }
  float* row = mask + ((size_t)b * HH + h) * WW;
  row[tid] = c0 ? 1.0f : 0.0f;
  row[tid + 256] = c1 ? 1.0f : 0.0f;
}

// ---------------------------------------------------------------------------
extern "C" void kernel_launch(void* const* d_in, const int* in_sizes, int n_in,
                              void* d_out, int out_size, void* d_ws, size_t ws_size,
                              hipStream_t stream) {
  const float* rois = (const float*)d_in[0];
  const float* probs = (const float*)d_in[1];
  const float* deltas = (const float*)d_in[2];
  const float* stdv = (const float*)d_in[3];
  float* out = (float*)d_out;
  float* det = out;                  // [8,100,6] = 4800 floats
  float* mask = out + BB * MAXI * 6; // [8,512,512]

  char* p = (char*)d_ws;
  unsigned long long* gkeys = (unsigned long long*)p; p += (size_t)BB * NPAD * 8;
  float* box     = (float*)p; p += (size_t)BB * NPAD * 16;
  float* score   = (float*)p; p += (size_t)BB * NPAD * 4;
  int*   cls     = (int*)p;   p += (size_t)BB * NPAD * 4;
  int*   valid   = (int*)p;   p += (size_t)BB * NPAD * 4;
  int*   partial = (int*)p;   p += (size_t)BB * 8 * NPAD * 4;
  int*   perm    = (int*)p;   p += (size_t)BB * NPAD * 4;

  k_refine<<<(BB * NPAD) / 4, 256, 0, stream>>>(rois, probs, deltas, stdv,
                                                score, cls, valid, box, gkeys);
  k_rankp<<<BB * 64, 256, 0, stream>>>(gkeys, partial);
  k_perm<<<BB * NPAD / 256, 256, 0, stream>>>(partial, perm);
  k_nms<<<BB, 64, 0, stream>>>(score, cls, valid, box, perm, det);
  k_mask<<<BB * HH, 256, 0, stream>>>(det, mask);
}